// Round 2
// baseline (1297.323 us; speedup 1.0000x reference)
//
#include <hip/hip_runtime.h>

// GNNModel: per-batch 12-node GCN, fused end-to-end.
// Baseline: all-fp32 VALU (correctness anchor; compute-bound ~0.6-1.1 ms).
// Block = 256 threads = 8 batches; thread (tr = tid>>5, tc = tid&31) owns
// batch tr, columns 4*tc..4*tc+3. h lives in LDS; t = h@W lives in registers
// so the Ahat mix is register-local.
//
// R1 fix: A = mask + I has diagonal 2 (mask's own diag=1 PLUS GCNConv's
// appended self-loop). deg already accounted for it; the stored Ahat didn't.

constexpr int NB   = 8;    // batches per block
constexpr int PP   = 12;   // planets (nodes)
constexpr int DIN  = 32;
constexpr int H    = 128;
constexpr int HO   = 64;   // H/2
constexpr int DOUT = 3;
constexpr int NL   = 3;    // GCN layers

__global__ __launch_bounds__(256, 2)
void gnn_fused(const float* __restrict__ x,       // [B,12,32]
               const float* __restrict__ W_in,    // [32,128]
               const float* __restrict__ b_in,    // [128]
               const float* __restrict__ W_gcn,   // [3,128,128]
               const float* __restrict__ b_gcn,   // [3,128]
               const float* __restrict__ W_out1,  // [128,64]
               const float* __restrict__ b_out1,  // [64]
               const float* __restrict__ W_out2,  // [64,3]
               const float* __restrict__ b_out2,  // [3]
               float* __restrict__ out)           // [B,3]
{
    __shared__ float x_lds[NB * PP * DIN];        // 12 KB
    __shared__ float h_lds[NB][PP][H];            // 48 KB
    __shared__ float Ahat[NB][PP][PP];            // 4.5 KB
    __shared__ float dinv_lds[NB][PP];            // 0.4 KB
    __shared__ float g_lds[NB][H];                // 4 KB
    __shared__ float o1_lds[NB][HO];              // 2 KB

    const int tid   = threadIdx.x;
    const int tc    = tid & 31;    // column group: cols 4*tc..4*tc+3
    const int tr    = tid >> 5;    // batch within block
    const int b0    = blockIdx.x * NB;
    const int batch = b0 + tr;

    // ---- stage x tile (block slice is contiguous: 8*12*32 = 3072 floats) ----
    {
        const float* xblk = x + (size_t)b0 * (PP * DIN);
        #pragma unroll
        for (int i = 0; i < (NB * PP * DIN) / 256; ++i)
            x_lds[tid + 256 * i] = xblk[tid + 256 * i];
    }
    __syncthreads();

    // ---- adjacency: Ahat = D^-1/2 (mask + I) D^-1/2, all fp32 (bit-exact mask) ----
    if (tc < PP) {
        const int i = tc;
        const float li = x_lds[tr * PP * DIN + i * DIN];   // lon[i] = x[b][i][0]
        float deg = 1.0f;                                   // the appended eye self-loop
        float row[PP];
        #pragma unroll
        for (int j = 0; j < PP; ++j) {
            const float lj = x_lds[tr * PP * DIN + j * DIN];
            float d = fabsf(li - lj);                       // < 360, so % 360 is identity
            d = fminf(d, 360.0f - d);                       // circular distance
            const float a = (d < 10.0f) ? 1.0f : 0.0f;      // includes diag (0 < 10)
            row[j] = (j == i) ? (a + 1.0f) : a;             // A = mask + eye: diag = 2
            deg += a;
        }
        dinv_lds[tr][i] = rsqrtf(fmaxf(deg, 1e-12f));
        #pragma unroll
        for (int j = 0; j < PP; ++j) Ahat[tr][i][j] = row[j];
    }
    __syncthreads();
    if (tc < PP) {
        const float di = dinv_lds[tr][tc];
        #pragma unroll
        for (int j = 0; j < PP; ++j)
            Ahat[tr][tc][j] *= di * dinv_lds[tr][j];
    }
    __syncthreads();

    // ---- input projection: h0 = x @ W_in + b_in (no relu) ----
    {
        float4 acc[PP];
        const float4 b4 = *(const float4*)&b_in[4 * tc];
        #pragma unroll
        for (int p = 0; p < PP; ++p) acc[p] = b4;

        #pragma unroll
        for (int f4 = 0; f4 < DIN / 4; ++f4) {
            const float4 w0 = *(const float4*)&W_in[(4 * f4 + 0) * H + 4 * tc];
            const float4 w1 = *(const float4*)&W_in[(4 * f4 + 1) * H + 4 * tc];
            const float4 w2 = *(const float4*)&W_in[(4 * f4 + 2) * H + 4 * tc];
            const float4 w3 = *(const float4*)&W_in[(4 * f4 + 3) * H + 4 * tc];
            #pragma unroll
            for (int p = 0; p < PP; ++p) {
                const float4 xq = *(const float4*)&x_lds[tr * PP * DIN + p * DIN + 4 * f4];
                acc[p].x += xq.x * w0.x + xq.y * w1.x + xq.z * w2.x + xq.w * w3.x;
                acc[p].y += xq.x * w0.y + xq.y * w1.y + xq.z * w2.y + xq.w * w3.y;
                acc[p].z += xq.x * w0.z + xq.y * w1.z + xq.z * w2.z + xq.w * w3.z;
                acc[p].w += xq.x * w0.w + xq.y * w1.w + xq.z * w2.w + xq.w * w3.w;
            }
        }
        #pragma unroll
        for (int p = 0; p < PP; ++p)
            *(float4*)&h_lds[tr][p][4 * tc] = acc[p];
    }
    __syncthreads();

    // ---- GCN layers: h = relu(Ahat @ (h @ W) + b) ----
    for (int l = 0; l < NL; ++l) {
        const float* __restrict__ Wl = W_gcn + (size_t)l * H * H;

        float4 t[PP];   // t = h @ Wl, this thread's [12 rows][4 cols] tile
        #pragma unroll
        for (int p = 0; p < PP; ++p) t[p] = make_float4(0.f, 0.f, 0.f, 0.f);

        #pragma unroll 2
        for (int k4 = 0; k4 < H / 4; ++k4) {
            const float4 w0 = *(const float4*)&Wl[(4 * k4 + 0) * H + 4 * tc];
            const float4 w1 = *(const float4*)&Wl[(4 * k4 + 1) * H + 4 * tc];
            const float4 w2 = *(const float4*)&Wl[(4 * k4 + 2) * H + 4 * tc];
            const float4 w3 = *(const float4*)&Wl[(4 * k4 + 3) * H + 4 * tc];
            #pragma unroll
            for (int p = 0; p < PP; ++p) {
                const float4 hq = *(const float4*)&h_lds[tr][p][4 * k4];
                t[p].x += hq.x * w0.x + hq.y * w1.x + hq.z * w2.x + hq.w * w3.x;
                t[p].y += hq.x * w0.y + hq.y * w1.y + hq.z * w2.y + hq.w * w3.y;
                t[p].z += hq.x * w0.z + hq.y * w1.z + hq.z * w2.z + hq.w * w3.z;
                t[p].w += hq.x * w0.w + hq.y * w1.w + hq.z * w2.w + hq.w * w3.w;
            }
        }
        __syncthreads();   // everyone done reading h_lds before we overwrite it

        const float4 bg = *(const float4*)&b_gcn[l * H + 4 * tc];
        #pragma unroll
        for (int p = 0; p < PP; ++p) {
            float4 nh = bg;
            #pragma unroll
            for (int j = 0; j < PP; ++j) {
                const float a = Ahat[tr][p][j];
                nh.x += a * t[j].x;
                nh.y += a * t[j].y;
                nh.z += a * t[j].z;
                nh.w += a * t[j].w;
            }
            nh.x = fmaxf(nh.x, 0.f);
            nh.y = fmaxf(nh.y, 0.f);
            nh.z = fmaxf(nh.z, 0.f);
            nh.w = fmaxf(nh.w, 0.f);
            *(float4*)&h_lds[tr][p][4 * tc] = nh;
        }
        __syncthreads();
    }

    // ---- mean pool over planets ----
    {
        float4 g4 = make_float4(0.f, 0.f, 0.f, 0.f);
        #pragma unroll
        for (int p = 0; p < PP; ++p) {
            const float4 hq = *(const float4*)&h_lds[tr][p][4 * tc];
            g4.x += hq.x; g4.y += hq.y; g4.z += hq.z; g4.w += hq.w;
        }
        const float inv = 1.0f / 12.0f;
        g4.x *= inv; g4.y *= inv; g4.z *= inv; g4.w *= inv;
        *(float4*)&g_lds[tr][4 * tc] = g4;
    }
    __syncthreads();

    // ---- head layer 1: o1 = relu(g @ W_out1 + b_out1), 2 outputs per thread ----
    #pragma unroll
    for (int oo = 0; oo < 2; ++oo) {
        const int o = tc + 32 * oo;
        float a = b_out1[o];
        #pragma unroll 4
        for (int k = 0; k < H; k += 4) {
            const float4 gq = *(const float4*)&g_lds[tr][k];
            a += gq.x * W_out1[(k + 0) * HO + o];
            a += gq.y * W_out1[(k + 1) * HO + o];
            a += gq.z * W_out1[(k + 2) * HO + o];
            a += gq.w * W_out1[(k + 3) * HO + o];
        }
        o1_lds[tr][o] = fmaxf(a, 0.f);
    }
    __syncthreads();

    // ---- head layer 2: out = o1 @ W_out2 + b_out2 ----
    if (tc < DOUT) {
        const int o = tc;
        float a = b_out2[o];
        #pragma unroll 8
        for (int k = 0; k < HO; ++k)
            a += o1_lds[tr][k] * W_out2[k * DOUT + o];
        out[(size_t)batch * DOUT + o] = a;
    }
}

extern "C" void kernel_launch(void* const* d_in, const int* in_sizes, int n_in,
                              void* d_out, int out_size, void* d_ws, size_t ws_size,
                              hipStream_t stream) {
    const float* x      = (const float*)d_in[0];
    const float* W_in   = (const float*)d_in[1];
    const float* b_in   = (const float*)d_in[2];
    const float* W_gcn  = (const float*)d_in[3];
    const float* b_gcn  = (const float*)d_in[4];
    const float* W_out1 = (const float*)d_in[5];
    const float* b_out1 = (const float*)d_in[6];
    const float* W_out2 = (const float*)d_in[7];
    const float* b_out2 = (const float*)d_in[8];
    float* outp         = (float*)d_out;

    const int B = in_sizes[0] / (PP * DIN);   // 65536
    dim3 grid(B / NB), block(256);
    hipLaunchKernelGGL(gnn_fused, grid, block, 0, stream,
                       x, W_in, b_in, W_gcn, b_gcn, W_out1, b_out1, W_out2, b_out2, outp);
}

// Round 3
// 522.262 us; speedup vs baseline: 2.4840x; 2.4840x over previous
//
#include <hip/hip_runtime.h>

// GNNModel fused via fp16 MFMA (16x16x32). Adjacency mask stays bit-exact fp32.
// Block = 4 batches = 48 rows; 4 waves, wave owns 32 N-cols (2 N-tiles).
// t = h@W and mix = Amat@t both on MFMA; Amat is the block-diagonal (48x64,
// zero-padded K) f16 normalized adjacency built once per block.

typedef _Float16 half8v __attribute__((ext_vector_type(8)));
typedef _Float16 half4v __attribute__((ext_vector_type(4)));
typedef float    float4v __attribute__((ext_vector_type(4)));

constexpr int PP = 12, DIN = 32, H = 128, HO = 64, DOUT = 3, NL = 3;
constexpr int NB = 4, ROWS = NB * PP;          // 48 rows per block
constexpr int XP = 40;                          // x_a row stride (halves), 80B, 16B-mult
constexpr int HP = 136;                         // h_a row stride, 272B, 16B-mult
constexpr int TP = 72;                          // tT row stride, 144B, 16B-mult
constexpr int AP = 72;                          // Amat row stride, 144B, 16B-mult

// ws layout in halves: WinT[128][32] @0 ; WgT[3][128][128] @4096 ; W1T[64][128] @53248
constexpr int WS_WG = 4096, WS_W1 = 53248, WS_TOT = 61440;

__global__ __launch_bounds__(256)
void prep_weights(const float* __restrict__ W_in, const float* __restrict__ W_gcn,
                  const float* __restrict__ W_out1, _Float16* __restrict__ ws)
{
    int e = blockIdx.x * 256 + threadIdx.x;
    if (e < WS_WG) {                        // WinT[n][k] = W_in[k][n]
        int n = e >> 5, k = e & 31;
        ws[e] = (_Float16)W_in[k * H + n];
    } else if (e < WS_W1) {                 // WgT[l][n][k] = W_gcn[l][k][n]
        int e2 = e - WS_WG;
        int l = e2 >> 14, r = e2 & 16383, n = r >> 7, k = r & 127;
        ws[e] = (_Float16)W_gcn[l * (H * H) + k * H + n];
    } else if (e < WS_TOT) {                // W1T[o][k] = W_out1[k][o]
        int e3 = e - WS_W1;
        int o = e3 >> 7, k = e3 & 127;
        ws[e] = (_Float16)W_out1[k * HO + o];
    }
}

__global__ __launch_bounds__(256, 2)
void gnn_mfma(const float* __restrict__ x,
              const float* __restrict__ b_in,
              const float* __restrict__ b_gcn,
              const float* __restrict__ b_out1,
              const float* __restrict__ W_out2,
              const float* __restrict__ b_out2,
              const _Float16* __restrict__ ws,
              float* __restrict__ out)
{
    __shared__ _Float16 x_a[ROWS][XP];      // 3.75 KB  x in A-layout (f16)
    __shared__ _Float16 h_a[ROWS][HP];      // 12.75 KB h in A-layout (f16)
    __shared__ _Float16 tT[H][TP];          // 18 KB    t col-major (B-operand for mix)
    __shared__ _Float16 Amat[ROWS][AP];     // 6.75 KB  block-diag adjacency, K padded to 64
    __shared__ float    lon_s[ROWS];
    __shared__ float    Atmp[NB][PP][PP];
    __shared__ float    dinv_s[NB][PP];
    __shared__ float    g_s[NB][H];
    __shared__ float    o1_s[NB][HO];

    const int tid = threadIdx.x;
    const int b0  = blockIdx.x * NB;
    const float* xblk = x + (size_t)b0 * (PP * DIN);

    // ---- stage x -> f16 A-layout; lon (exact fp32); zero Amat + tT K-pad ----
    #pragma unroll
    for (int i = 0; i < 2; ++i) {
        int qi = tid + 256 * i;
        if (qi < ROWS * DIN / 4) {
            float4 v = ((const float4*)xblk)[qi];
            int r = qi >> 3, c = (qi & 7) * 4;
            half4v hv;
            hv[0] = (_Float16)v.x; hv[1] = (_Float16)v.y;
            hv[2] = (_Float16)v.z; hv[3] = (_Float16)v.w;
            *(half4v*)&x_a[r][c] = hv;
        }
    }
    if (tid < ROWS) lon_s[tid] = xblk[tid * DIN];        // x[b][p][0], fp32 exact
    #pragma unroll
    for (int i = 0; i < 7; ++i) {                        // 48*72*2/4 = 1728 dwords
        int idx = tid + 256 * i;
        if (idx < ROWS * AP / 2) ((unsigned*)Amat)[idx] = 0u;
    }
    #pragma unroll
    for (int i = 0; i < 4; ++i) {                        // tT[n][48..63] = 0 (K pad)
        int idx = tid + 256 * i;                         // 128 rows * 8 dwords = 1024
        int n = idx >> 3, c = (idx & 7) * 2;
        *(unsigned*)&tT[n][48 + c] = 0u;
    }
    __syncthreads();

    // ---- adjacency (bit-exact fp32 mask; A = mask + I has diag 2) ----
    if (tid < ROWS) {
        int b = tid / 12, i = tid - 12 * b;
        float li = lon_s[b * 12 + i];
        float deg = 1.0f;                                 // appended eye self-loop
        float row[PP];
        #pragma unroll
        for (int j = 0; j < PP; ++j) {
            float lj = lon_s[b * 12 + j];
            float d = fabsf(li - lj);
            d = fminf(d, 360.0f - d);
            float a = (d < 10.0f) ? 1.0f : 0.0f;
            row[j] = (j == i) ? (a + 1.0f) : a;
            deg += a;
        }
        dinv_s[b][i] = rsqrtf(fmaxf(deg, 1e-12f));
        #pragma unroll
        for (int j = 0; j < PP; ++j) Atmp[b][i][j] = row[j];
    }
    __syncthreads();
    if (tid < ROWS) {
        int b = tid / 12, i = tid - 12 * b;
        float di = dinv_s[b][i];
        #pragma unroll
        for (int j = 0; j < PP; ++j)
            Amat[b * 12 + i][b * 12 + j] = (_Float16)(Atmp[b][i][j] * di * dinv_s[b][j]);
    }
    __syncthreads();

    // ---- MFMA phases ----
    const int lane = tid & 63, wave = tid >> 6;
    const int q = lane >> 4, qm = lane & 15;
    const int col0 = wave * 32 + qm, col1 = col0 + 16;    // wave's two N-tile cols
    const _Float16* WinT = ws;                            // [128][32]
    const _Float16* WgT  = ws + WS_WG;                    // [3][128][128]

    // proj: h0 = x @ W_in + b_in (no relu), K=32 = one MFMA step
    {
        half8v bw0 = *(const half8v*)&WinT[col0 * DIN + 8 * q];
        half8v bw1 = *(const half8v*)&WinT[col1 * DIN + 8 * q];
        float4v c[3][2];
        #pragma unroll
        for (int mt = 0; mt < 3; ++mt) { c[mt][0] = 0; c[mt][1] = 0; }
        #pragma unroll
        for (int mt = 0; mt < 3; ++mt) {
            half8v a = *(const half8v*)&x_a[mt * 16 + qm][8 * q];
            c[mt][0] = __builtin_amdgcn_mfma_f32_16x16x32_f16(a, bw0, c[mt][0], 0, 0, 0);
            c[mt][1] = __builtin_amdgcn_mfma_f32_16x16x32_f16(a, bw1, c[mt][1], 0, 0, 0);
        }
        float bi0 = b_in[col0], bi1 = b_in[col1];
        #pragma unroll
        for (int mt = 0; mt < 3; ++mt)
            #pragma unroll
            for (int r = 0; r < 4; ++r) {
                int row = mt * 16 + q * 4 + r;
                h_a[row][col0] = (_Float16)(c[mt][0][r] + bi0);
                h_a[row][col1] = (_Float16)(c[mt][1][r] + bi1);
            }
    }
    __syncthreads();

    // GCN layers: h = relu(Amat @ (h @ Wl) + b)
    for (int l = 0; l < NL; ++l) {
        const _Float16* Wl = WgT + l * (H * H);

        half8v bw[2][4];
        #pragma unroll
        for (int n = 0; n < 2; ++n)
            #pragma unroll
            for (int k = 0; k < 4; ++k)
                bw[n][k] = *(const half8v*)&Wl[(col0 + 16 * n) * H + k * 32 + 8 * q];

        float4v c[3][2];
        #pragma unroll
        for (int mt = 0; mt < 3; ++mt) { c[mt][0] = 0; c[mt][1] = 0; }
        #pragma unroll
        for (int mt = 0; mt < 3; ++mt)
            #pragma unroll
            for (int k = 0; k < 4; ++k) {
                half8v a = *(const half8v*)&h_a[mt * 16 + qm][k * 32 + 8 * q];
                c[mt][0] = __builtin_amdgcn_mfma_f32_16x16x32_f16(a, bw[0][k], c[mt][0], 0, 0, 0);
                c[mt][1] = __builtin_amdgcn_mfma_f32_16x16x32_f16(a, bw[1][k], c[mt][1], 0, 0, 0);
            }

        // t -> tT (col-major): C-layout lane holds 4 consecutive rows at fixed col
        #pragma unroll
        for (int mt = 0; mt < 3; ++mt)
            #pragma unroll
            for (int n = 0; n < 2; ++n) {
                half4v hv;
                #pragma unroll
                for (int r = 0; r < 4; ++r) hv[r] = (_Float16)c[mt][n][r];
                *(half4v*)&tT[col0 + 16 * n][mt * 16 + q * 4] = hv;
            }
        __syncthreads();

        // mix: D = Amat(48x64, block-diag) @ t(64x128 via tT, rows 48..63 zero)
        half8v bt[2][2];
        #pragma unroll
        for (int n = 0; n < 2; ++n)
            #pragma unroll
            for (int k = 0; k < 2; ++k)
                bt[n][k] = *(const half8v*)&tT[col0 + 16 * n][k * 32 + 8 * q];

        float4v d[3][2];
        #pragma unroll
        for (int mt = 0; mt < 3; ++mt) { d[mt][0] = 0; d[mt][1] = 0; }
        #pragma unroll
        for (int mt = 0; mt < 3; ++mt)
            #pragma unroll
            for (int k = 0; k < 2; ++k) {
                half8v a = *(const half8v*)&Amat[mt * 16 + qm][k * 32 + 8 * q];
                d[mt][0] = __builtin_amdgcn_mfma_f32_16x16x32_f16(a, bt[0][k], d[mt][0], 0, 0, 0);
                d[mt][1] = __builtin_amdgcn_mfma_f32_16x16x32_f16(a, bt[1][k], d[mt][1], 0, 0, 0);
            }

        float bg0 = b_gcn[l * H + col0], bg1 = b_gcn[l * H + col1];
        #pragma unroll
        for (int mt = 0; mt < 3; ++mt)
            #pragma unroll
            for (int r = 0; r < 4; ++r) {
                int row = mt * 16 + q * 4 + r;
                h_a[row][col0] = (_Float16)fmaxf(d[mt][0][r] + bg0, 0.0f);
                h_a[row][col1] = (_Float16)fmaxf(d[mt][1][r] + bg1, 0.0f);
            }
        __syncthreads();
    }

    // ---- mean pool ----
    {
        int b4 = tid >> 6, tc = tid & 63;                 // 2 cols per thread
        int c = 2 * tc;
        float s0 = 0.f, s1 = 0.f;
        #pragma unroll
        for (int p = 0; p < PP; ++p) {
            s0 += (float)h_a[b4 * 12 + p][c];
            s1 += (float)h_a[b4 * 12 + p][c + 1];
        }
        g_s[b4][c]     = s0 * (1.0f / 12.0f);
        g_s[b4][c + 1] = s1 * (1.0f / 12.0f);
    }
    __syncthreads();

    // ---- head1: o1 = relu(g @ W_out1 + b_out1); W1T rows contiguous per thread ----
    {
        int b4 = tid >> 6, o = tid & 63;
        float acc = b_out1[o];
        const _Float16* wr = ws + WS_W1 + o * H;
        #pragma unroll
        for (int kk = 0; kk < H / 8; ++kk) {
            half8v wv = *(const half8v*)&wr[8 * kk];
            #pragma unroll
            for (int j = 0; j < 8; ++j) acc += g_s[b4][8 * kk + j] * (float)wv[j];
        }
        o1_s[b4][o] = fmaxf(acc, 0.0f);
    }
    __syncthreads();

    // ---- head2: out = o1 @ W_out2 + b_out2 (fp32) ----
    if (tid < NB * DOUT) {
        int b = tid / DOUT, o = tid - DOUT * b;
        float acc = b_out2[o];
        #pragma unroll 8
        for (int k = 0; k < HO; ++k)
            acc += o1_s[b][k] * W_out2[k * DOUT + o];
        out[(size_t)(b0 + b) * DOUT + o] = acc;
    }
}

extern "C" void kernel_launch(void* const* d_in, const int* in_sizes, int n_in,
                              void* d_out, int out_size, void* d_ws, size_t ws_size,
                              hipStream_t stream) {
    const float* x      = (const float*)d_in[0];
    const float* W_in   = (const float*)d_in[1];
    const float* b_in   = (const float*)d_in[2];
    const float* W_gcn  = (const float*)d_in[3];
    const float* b_gcn  = (const float*)d_in[4];
    const float* W_out1 = (const float*)d_in[5];
    const float* b_out1 = (const float*)d_in[6];
    const float* W_out2 = (const float*)d_in[7];
    const float* b_out2 = (const float*)d_in[8];
    float* outp         = (float*)d_out;
    _Float16* wsh       = (_Float16*)d_ws;

    const int B = in_sizes[0] / (PP * DIN);               // 65536

    hipLaunchKernelGGL(prep_weights, dim3((WS_TOT + 255) / 256), dim3(256), 0, stream,
                       W_in, W_gcn, W_out1, wsh);
    hipLaunchKernelGGL(gnn_mfma, dim3(B / NB), dim3(256), 0, stream,
                       x, b_in, b_gcn, b_out1, W_out2, b_out2, wsh, outp);
}